// Round 10
// baseline (53.808 us; speedup 1.0000x reference)
//
#include <hip/hip_runtime.h>
#include <hip/hip_bf16.h>

// QLoRA SwiGLU MLP, B=16 tokens, d=4096, h=11008, r=2.
// tile(wq,(1,4)) => x @ W^T == fold4(x) @ wq^T  (skinny GEMM, K = in/4).
// R10: 3-kernel pipeline. gateup epilogue atomically folds silu(g)*u into
// hfold[16][2752] f32 AND accumulates t2 = hvec·a2^T partials -> k_prep2 and
// the hvecT round-trip are gone. k_down splits each 16-col tile across 2
// blocks (K-halves) with atomicAdd into zeroed out -> 8 waves/CU, 256-VGPR
// budget (R8's down was 4 waves/CU). prep1 zeroes hfold/T2/out each replay.
// MFMA 16x16x32 bf16; weights f32->bf16 in-register (hw cvt, RNE).
// Fragment maps (verified): A/B: own-idx = lane&15, k = (lane>>4)*8+j;
// C/D: col(n) = lane&15, row(m) = (lane>>4)*4+reg.

#define NB     16
#define DMODEL 4096
#define HID    11008
#define DQ     1024   // DMODEL/4
#define HQ     2752   // HID/4

// workspace layout (float offsets)
#define XSB_OFF 0         // xs bf16 [16][1024] = 8192 floats
#define T1_OFF  8192      // [16][2] f32
#define T3_OFF  8224
#define HF_OFF  8256      // hfold f32 [16][2752] = 44032 floats
#define T2_OFF  52288     // [16][2] f32  (zeroed with hfold by prep1)

typedef __attribute__((ext_vector_type(8))) short bf16x8;
typedef __attribute__((ext_vector_type(4))) float f32x4;

__device__ __forceinline__ unsigned short f2bfh(float f) {
  __hip_bfloat16 h = __float2bfloat16(f);   // v_cvt, RNE
  return __builtin_bit_cast(unsigned short, h);
}
__device__ __forceinline__ unsigned pack2(float lo, float hi) {
  return (unsigned)f2bfh(lo) | ((unsigned)f2bfh(hi) << 16);
}
__device__ __forceinline__ bf16x8 cvt8(const float4 a, const float4 b) {
  uint4 u = make_uint4(pack2(a.x, a.y), pack2(a.z, a.w),
                       pack2(b.x, b.y), pack2(b.z, b.w));
  return __builtin_bit_cast(bf16x8, u);
}

// ---------------------------------------------------------------------------
// prep1: xs[b][j] = fold4(x) stored bf16; t1,t3 = LoRA A dots; zero
// hfold+T2 (44064 floats) and out (65536 floats) for this replay's atomics.
__global__ __launch_bounds__(256) void k_prep1(const float* __restrict__ x,
                                               const float* __restrict__ a1,
                                               const float* __restrict__ a3,
                                               float* __restrict__ ws,
                                               float* __restrict__ out) {
  const int b = blockIdx.x, t = threadIdx.x;
  const int gid = b * 256 + t;                 // 0..4095
  const float4 z4 = make_float4(0.f, 0.f, 0.f, 0.f);
  // zero hfold + T2: 44064 floats = 11016 float4 from HF_OFF (16B aligned)
  for (int i = gid; i < 11016; i += 4096)
    ((float4*)(ws + HF_OFF))[i] = z4;
  // zero out: 65536 floats = 16384 float4
  for (int i = gid; i < 16384; i += 4096)
    ((float4*)out)[i] = z4;

  const float4* x4  = (const float4*)(x) + b * (DMODEL / 4);
  const float4* a14 = (const float4*)a1;
  const float4* a34 = (const float4*)a3;
  float4 xs = z4;
  float s10 = 0.f, s11 = 0.f, s30 = 0.f, s31 = 0.f;
#pragma unroll
  for (int k = 0; k < 4; ++k) {
    float4 xv  = x4[k * 256 + t];
    xs.x += xv.x; xs.y += xv.y; xs.z += xv.z; xs.w += xv.w;
    float4 a10 = a14[k * 256 + t];
    float4 a11 = a14[1024 + k * 256 + t];
    float4 a30 = a34[k * 256 + t];
    float4 a31 = a34[1024 + k * 256 + t];
    s10 += xv.x * a10.x + xv.y * a10.y + xv.z * a10.z + xv.w * a10.w;
    s11 += xv.x * a11.x + xv.y * a11.y + xv.z * a11.z + xv.w * a11.w;
    s30 += xv.x * a30.x + xv.y * a30.y + xv.z * a30.z + xv.w * a30.w;
    s31 += xv.x * a31.x + xv.y * a31.y + xv.z * a31.z + xv.w * a31.w;
  }
  ((uint2*)(ws + XSB_OFF))[b * 256 + t] =
      make_uint2(pack2(xs.x, xs.y), pack2(xs.z, xs.w));

  __shared__ float4 rb[256];
  rb[t] = make_float4(s10, s11, s30, s31);
  __syncthreads();
  for (int s = 128; s > 0; s >>= 1) {
    if (t < s) {
      rb[t].x += rb[t + s].x; rb[t].y += rb[t + s].y;
      rb[t].z += rb[t + s].z; rb[t].w += rb[t + s].w;
    }
    __syncthreads();
  }
  if (t == 0) {
    ws[T1_OFF + b * 2]     = rb[0].x;
    ws[T1_OFF + b * 2 + 1] = rb[0].y;
    ws[T3_OFF + b * 2]     = rb[0].z;
    ws[T3_OFF + b * 2 + 1] = rb[0].w;
  }
}

// ---------------------------------------------------------------------------
// gateup: 688 blocks x 256 thr (4 waves). Tile = 16 out cols; wave w owns
// K-chunk [w*256, w*256+256) = 8 kk. LDS reduce; wave-0 epilogue computes
// v = silu(g)*u, atomicAdds v into hfold[n][oo%HQ] and t2 partials into T2.
__global__ __launch_bounds__(256) void k_gateup(const float* __restrict__ w1q,
                                                const float* __restrict__ w3q,
                                                const float* __restrict__ b1,
                                                const float* __restrict__ b3,
                                                const float* __restrict__ a2,
                                                float* __restrict__ ws) {
  __shared__ float red[4][8][64];
  const int t = threadIdx.x, w = t >> 6, l = t & 63;
  const int tile = blockIdx.x;
  const int n  = l & 15;            // token col / weight row selector
  const int kb = (l >> 4) * 8;      // k sub-offset within each 32-block
  const int o  = tile * 16 + n;
  const unsigned short* xsb = (const unsigned short*)(ws + XSB_OFF);

  f32x4 acc1 = {0.f, 0.f, 0.f, 0.f}, acc3 = {0.f, 0.f, 0.f, 0.f};
  const int k0 = w * 256;
#pragma unroll
  for (int kk = 0; kk < 8; ++kk) {
    const int kabs = k0 + kk * 32 + kb;
    const float4* p1 = (const float4*)(w1q + (size_t)o * DQ + kabs);
    const float4* p3 = (const float4*)(w3q + (size_t)o * DQ + kabs);
    const bf16x8 bb = *(const bf16x8*)(xsb + n * DQ + kabs);
    const bf16x8 a1f = cvt8(p1[0], p1[1]);
    const bf16x8 a3f = cvt8(p3[0], p3[1]);
    acc1 = __builtin_amdgcn_mfma_f32_16x16x32_bf16(a1f, bb, acc1, 0, 0, 0);
    acc3 = __builtin_amdgcn_mfma_f32_16x16x32_bf16(a3f, bb, acc3, 0, 0, 0);
  }
#pragma unroll
  for (int r = 0; r < 4; ++r) {
    red[w][r][l]     = acc1[r];
    red[w][r + 4][l] = acc3[r];
  }
  __syncthreads();
  if (w == 0) {
    const float t10 = ws[T1_OFF + 2 * n], t11 = ws[T1_OFF + 2 * n + 1];
    const float t30 = ws[T3_OFF + 2 * n], t31 = ws[T3_OFF + 2 * n + 1];
    const int m4 = (l >> 4) * 4;
    float p0 = 0.f, p1p = 0.f;      // t2 partials for token n
#pragma unroll
    for (int r = 0; r < 4; ++r) {
      float g0 = 0.f, u0 = 0.f;
#pragma unroll
      for (int ww = 0; ww < 4; ++ww) {
        g0 += red[ww][r][l];
        u0 += red[ww][r + 4][l];
      }
      const int oo = tile * 16 + m4 + r;
      const float g = g0 + 0.5f * (t10 * b1[2 * oo] + t11 * b1[2 * oo + 1]);
      const float u = u0 + 0.5f * (t30 * b3[2 * oo] + t31 * b3[2 * oo + 1]);
      const float v = (g / (1.f + __expf(-g))) * u;
      const int jj = oo % HQ;        // folded column
      atomicAdd(&ws[HF_OFF + n * HQ + jj], v);
      p0  += v * a2[oo];
      p1p += v * a2[HID + oo];
    }
    // reduce t2 partials across the 4 lanes sharing token n (l, l+16, ...)
    p0  += __shfl_xor(p0, 16);  p0  += __shfl_xor(p0, 32);
    p1p += __shfl_xor(p1p, 16); p1p += __shfl_xor(p1p, 32);
    if (l < 16) {
      atomicAdd(&ws[T2_OFF + 2 * n], p0);
      atomicAdd(&ws[T2_OFF + 2 * n + 1], p1p);
    }
  }
}

// ---------------------------------------------------------------------------
// down: 512 blocks x 256 thr (4 waves). Block = (tile, K-half); global wave
// g = half*4+w covers kk-range {11,11,11,11,11,11,10,10} of K=2752. B-frag
// from hfold f32 (cvt in-register). atomicAdd into zeroed out; LoRA in half 0.
__global__ __launch_bounds__(256) void k_down(const float* __restrict__ w2q,
                                              const float* __restrict__ b2,
                                              const float* __restrict__ ws,
                                              float* __restrict__ out) {
  __shared__ float red[4][4][64];
  const int t = threadIdx.x, w = t >> 6, l = t & 63;
  const int tile = blockIdx.x >> 1, half = blockIdx.x & 1;
  const int g = half * 4 + w;
  const int n  = l & 15;
  const int kb = (l >> 4) * 8;
  const int o  = tile * 16 + n;
  const float* hf = ws + HF_OFF;

  f32x4 acc = {0.f, 0.f, 0.f, 0.f};
  const int kks  = (g < 6) ? g * 11 : 66 + (g - 6) * 10;
  const int klen = (g < 6) ? 11 : 10;
#pragma unroll
  for (int kk = 0; kk < 11; ++kk) {
    if (kk < klen) {                      // wave-uniform guard
      const int kabs = (kks + kk) * 32 + kb;
      const float4* p2 = (const float4*)(w2q + (size_t)o * HQ + kabs);
      const float4* pb = (const float4*)(hf + (size_t)n * HQ + kabs);
      const bf16x8 af = cvt8(p2[0], p2[1]);
      const bf16x8 bb = cvt8(pb[0], pb[1]);
      acc = __builtin_amdgcn_mfma_f32_16x16x32_bf16(af, bb, acc, 0, 0, 0);
    }
  }
#pragma unroll
  for (int r = 0; r < 4; ++r) red[w][r][l] = acc[r];
  __syncthreads();
  if (w == 0) {
    const float t20 = ws[T2_OFF + 2 * n], t21 = ws[T2_OFF + 2 * n + 1];
    const int m4 = (l >> 4) * 4;
#pragma unroll
    for (int r = 0; r < 4; ++r) {
      float v = red[0][r][l] + red[1][r][l] + red[2][r][l] + red[3][r][l];
      const int oo = tile * 16 + m4 + r;
      if (half == 0)
        v += 0.5f * (t20 * b2[2 * oo] + t21 * b2[2 * oo + 1]);
      atomicAdd(&out[n * DMODEL + oo], v);
    }
  }
}

// ---------------------------------------------------------------------------
extern "C" void kernel_launch(void* const* d_in, const int* in_sizes, int n_in,
                              void* d_out, int out_size, void* d_ws, size_t ws_size,
                              hipStream_t stream) {
  const float* x   = (const float*)d_in[0];
  const float* w1q = (const float*)d_in[1];
  const float* a1  = (const float*)d_in[2];
  const float* b1  = (const float*)d_in[3];
  const float* w3q = (const float*)d_in[4];
  const float* a3  = (const float*)d_in[5];
  const float* b3  = (const float*)d_in[6];
  const float* w2q = (const float*)d_in[7];
  const float* a2  = (const float*)d_in[8];
  const float* b2  = (const float*)d_in[9];
  float* out = (float*)d_out;
  float* ws  = (float*)d_ws;

  k_prep1<<<16, 256, 0, stream>>>(x, a1, a3, ws, out);
  k_gateup<<<HID / 16, 256, 0, stream>>>(w1q, w3q, b1, b3, a2, ws);
  k_down<<<2 * (DMODEL / 16), 256, 0, stream>>>(w2q, b2, ws, out);
}

// Round 11
// 53.802 us; speedup vs baseline: 1.0001x; 1.0001x over previous
//
#include <hip/hip_runtime.h>
#include <hip/hip_bf16.h>

// QLoRA SwiGLU MLP, B=16 tokens, d=4096, h=11008, r=2.
// tile(wq,(1,4)) => x @ W^T == fold4(x) @ wq^T  (skinny GEMM, K = in/4).
// R11: R10 pipeline + hand-rolled 4-deep register prefetch. R10 counters
// showed VGPR=44 -> depth-1 load pipeline -> 2 TB/s latency-serialized
// (gateup 43.8us, VALUBusy 2.4%). Four named register sets, rolling
// PF(k+4); sched_barrier(0); MM(k) keeps ~20 loads/lane in flight.
// 256-thr blocks (4 waves) -> 256-VGPR cap, no spill cliff.
// MFMA 16x16x32 bf16; fragment maps (verified): A/B: own=lane&15,
// k=(lane>>4)*8+j; C/D: col=lane&15, row=(lane>>4)*4+reg.

#define NB     16
#define DMODEL 4096
#define HID    11008
#define DQ     1024   // DMODEL/4
#define HQ     2752   // HID/4

// workspace layout (float offsets)
#define XSB_OFF 0         // xs bf16 [16][1024] = 8192 floats
#define T1_OFF  8192      // [16][2] f32
#define T3_OFF  8224
#define HF_OFF  8256      // hfold f32 [16][2752] = 44032 floats
#define T2_OFF  52288     // [16][2] f32  (zeroed with hfold by prep1)

typedef __attribute__((ext_vector_type(8))) short bf16x8;
typedef __attribute__((ext_vector_type(4))) float f32x4;

__device__ __forceinline__ unsigned short f2bfh(float f) {
  __hip_bfloat16 h = __float2bfloat16(f);   // v_cvt, RNE
  return __builtin_bit_cast(unsigned short, h);
}
__device__ __forceinline__ unsigned pack2(float lo, float hi) {
  return (unsigned)f2bfh(lo) | ((unsigned)f2bfh(hi) << 16);
}
__device__ __forceinline__ bf16x8 cvt8(const float4 a, const float4 b) {
  uint4 u = make_uint4(pack2(a.x, a.y), pack2(a.z, a.w),
                       pack2(b.x, b.y), pack2(b.z, b.w));
  return __builtin_bit_cast(bf16x8, u);
}

// ---------------------------------------------------------------------------
// prep1: xs[b][j] = fold4(x) stored bf16; t1,t3 = LoRA A dots; zero
// hfold+T2 and out for this replay's atomics.
__global__ __launch_bounds__(256) void k_prep1(const float* __restrict__ x,
                                               const float* __restrict__ a1,
                                               const float* __restrict__ a3,
                                               float* __restrict__ ws,
                                               float* __restrict__ out) {
  const int b = blockIdx.x, t = threadIdx.x;
  const int gid = b * 256 + t;                 // 0..4095
  const float4 z4 = make_float4(0.f, 0.f, 0.f, 0.f);
  for (int i = gid; i < 11016; i += 4096)      // hfold + T2
    ((float4*)(ws + HF_OFF))[i] = z4;
  for (int i = gid; i < 16384; i += 4096)      // out
    ((float4*)out)[i] = z4;

  const float4* x4  = (const float4*)(x) + b * (DMODEL / 4);
  const float4* a14 = (const float4*)a1;
  const float4* a34 = (const float4*)a3;
  float4 xs = z4;
  float s10 = 0.f, s11 = 0.f, s30 = 0.f, s31 = 0.f;
#pragma unroll
  for (int k = 0; k < 4; ++k) {
    float4 xv  = x4[k * 256 + t];
    xs.x += xv.x; xs.y += xv.y; xs.z += xv.z; xs.w += xv.w;
    float4 a10 = a14[k * 256 + t];
    float4 a11 = a14[1024 + k * 256 + t];
    float4 a30 = a34[k * 256 + t];
    float4 a31 = a34[1024 + k * 256 + t];
    s10 += xv.x * a10.x + xv.y * a10.y + xv.z * a10.z + xv.w * a10.w;
    s11 += xv.x * a11.x + xv.y * a11.y + xv.z * a11.z + xv.w * a11.w;
    s30 += xv.x * a30.x + xv.y * a30.y + xv.z * a30.z + xv.w * a30.w;
    s31 += xv.x * a31.x + xv.y * a31.y + xv.z * a31.z + xv.w * a31.w;
  }
  ((uint2*)(ws + XSB_OFF))[b * 256 + t] =
      make_uint2(pack2(xs.x, xs.y), pack2(xs.z, xs.w));

  __shared__ float4 rb[256];
  rb[t] = make_float4(s10, s11, s30, s31);
  __syncthreads();
  for (int s = 128; s > 0; s >>= 1) {
    if (t < s) {
      rb[t].x += rb[t + s].x; rb[t].y += rb[t + s].y;
      rb[t].z += rb[t + s].z; rb[t].w += rb[t + s].w;
    }
    __syncthreads();
  }
  if (t == 0) {
    ws[T1_OFF + b * 2]     = rb[0].x;
    ws[T1_OFF + b * 2 + 1] = rb[0].y;
    ws[T3_OFF + b * 2]     = rb[0].z;
    ws[T3_OFF + b * 2 + 1] = rb[0].w;
  }
}

// ---------------------------------------------------------------------------
// gateup: 688 blocks x 256 thr (4 waves). Tile = 16 out cols; wave w owns
// K-chunk [w*256, w*256+256) = 8 kk. 4-set rolling register pipeline.
#define GU_PF(KK, W1A, W1B, W3A, W3B, XB) do {                              \
    const int _ka = k0 + (KK) * 32 + kb;                                    \
    const float4* _p1 = (const float4*)(w1q + (size_t)o * DQ + _ka);        \
    const float4* _p3 = (const float4*)(w3q + (size_t)o * DQ + _ka);        \
    W1A = _p1[0]; W1B = _p1[1];                                             \
    W3A = _p3[0]; W3B = _p3[1];                                             \
    XB  = *(const bf16x8*)(xsb + n * DQ + _ka);                             \
  } while (0)

#define GU_MM(W1A, W1B, W3A, W3B, XB) do {                                  \
    acc1 = __builtin_amdgcn_mfma_f32_16x16x32_bf16(cvt8(W1A, W1B), XB,      \
                                                   acc1, 0, 0, 0);          \
    acc3 = __builtin_amdgcn_mfma_f32_16x16x32_bf16(cvt8(W3A, W3B), XB,      \
                                                   acc3, 0, 0, 0);          \
  } while (0)

#define SB __builtin_amdgcn_sched_barrier(0)

__global__ __launch_bounds__(256) void k_gateup(const float* __restrict__ w1q,
                                                const float* __restrict__ w3q,
                                                const float* __restrict__ b1,
                                                const float* __restrict__ b3,
                                                const float* __restrict__ a2,
                                                float* __restrict__ ws) {
  __shared__ float red[4][8][64];
  const int t = threadIdx.x, w = t >> 6, l = t & 63;
  const int tile = blockIdx.x;
  const int n  = l & 15;            // token col / weight row selector
  const int kb = (l >> 4) * 8;      // k sub-offset within each 32-block
  const int o  = tile * 16 + n;
  const int k0 = w * 256;
  const unsigned short* xsb = (const unsigned short*)(ws + XSB_OFF);

  f32x4 acc1 = {0.f, 0.f, 0.f, 0.f}, acc3 = {0.f, 0.f, 0.f, 0.f};

  float4 p0a, p0b, q0a, q0b;  bf16x8 x0;      // set 0
  float4 p1a, p1b, q1a, q1b;  bf16x8 x1;      // set 1
  float4 p2a, p2b, q2a, q2b;  bf16x8 x2;      // set 2
  float4 p3a, p3b, q3a, q3b;  bf16x8 x3;      // set 3

  GU_PF(0, p0a, p0b, q0a, q0b, x0);
  GU_PF(1, p1a, p1b, q1a, q1b, x1);
  GU_PF(2, p2a, p2b, q2a, q2b, x2);
  GU_PF(3, p3a, p3b, q3a, q3b, x3);
  SB;
  GU_MM(p0a, p0b, q0a, q0b, x0);  GU_PF(4, p0a, p0b, q0a, q0b, x0);  SB;
  GU_MM(p1a, p1b, q1a, q1b, x1);  GU_PF(5, p1a, p1b, q1a, q1b, x1);  SB;
  GU_MM(p2a, p2b, q2a, q2b, x2);  GU_PF(6, p2a, p2b, q2a, q2b, x2);  SB;
  GU_MM(p3a, p3b, q3a, q3b, x3);  GU_PF(7, p3a, p3b, q3a, q3b, x3);  SB;
  GU_MM(p0a, p0b, q0a, q0b, x0);
  GU_MM(p1a, p1b, q1a, q1b, x1);
  GU_MM(p2a, p2b, q2a, q2b, x2);
  GU_MM(p3a, p3b, q3a, q3b, x3);

#pragma unroll
  for (int r = 0; r < 4; ++r) {
    red[w][r][l]     = acc1[r];
    red[w][r + 4][l] = acc3[r];
  }
  __syncthreads();
  if (w == 0) {
    const float t10 = ws[T1_OFF + 2 * n], t11 = ws[T1_OFF + 2 * n + 1];
    const float t30 = ws[T3_OFF + 2 * n], t31 = ws[T3_OFF + 2 * n + 1];
    const int m4 = (l >> 4) * 4;
    float s0 = 0.f, s1 = 0.f;       // t2 partials for token n
#pragma unroll
    for (int r = 0; r < 4; ++r) {
      float g0 = 0.f, u0 = 0.f;
#pragma unroll
      for (int ww = 0; ww < 4; ++ww) {
        g0 += red[ww][r][l];
        u0 += red[ww][r + 4][l];
      }
      const int oo = tile * 16 + m4 + r;
      const float g = g0 + 0.5f * (t10 * b1[2 * oo] + t11 * b1[2 * oo + 1]);
      const float u = u0 + 0.5f * (t30 * b3[2 * oo] + t31 * b3[2 * oo + 1]);
      const float v = (g / (1.f + __expf(-g))) * u;
      atomicAdd(&ws[HF_OFF + n * HQ + (oo % HQ)], v);
      s0 += v * a2[oo];
      s1 += v * a2[HID + oo];
    }
    s0 += __shfl_xor(s0, 16);  s0 += __shfl_xor(s0, 32);
    s1 += __shfl_xor(s1, 16);  s1 += __shfl_xor(s1, 32);
    if (l < 16) {
      atomicAdd(&ws[T2_OFF + 2 * n], s0);
      atomicAdd(&ws[T2_OFF + 2 * n + 1], s1);
    }
  }
}

// ---------------------------------------------------------------------------
// down: 512 blocks x 256 thr (4 waves). Block = (tile, K-half); global wave
// g = half*4+w covers kk {11x6,10x2} of K=2752. 4-set 1-kk rolling pipeline.
#define DN_PF(KK, WA, WB, HA, HB) do {                                      \
    const int _ka = (kks + (KK)) * 32 + kb;                                 \
    const float4* _p2 = (const float4*)(w2q + (size_t)o * HQ + _ka);        \
    const float4* _pb = (const float4*)(hf + (size_t)n * HQ + _ka);         \
    WA = _p2[0]; WB = _p2[1]; HA = _pb[0]; HB = _pb[1];                     \
  } while (0)

#define DN_MM(WA, WB, HA, HB)                                               \
  acc = __builtin_amdgcn_mfma_f32_16x16x32_bf16(cvt8(WA, WB),               \
                                                cvt8(HA, HB), acc, 0, 0, 0)

__global__ __launch_bounds__(256) void k_down(const float* __restrict__ w2q,
                                              const float* __restrict__ b2,
                                              const float* __restrict__ ws,
                                              float* __restrict__ out) {
  __shared__ float red[4][4][64];
  const int t = threadIdx.x, w = t >> 6, l = t & 63;
  const int tile = blockIdx.x >> 1, half = blockIdx.x & 1;
  const int g = half * 4 + w;
  const int n  = l & 15;
  const int kb = (l >> 4) * 8;
  const int o  = tile * 16 + n;
  const float* hf = ws + HF_OFF;
  const int kks  = (g < 6) ? g * 11 : 66 + (g - 6) * 10;
  const int klen = (g < 6) ? 11 : 10;

  f32x4 acc = {0.f, 0.f, 0.f, 0.f};
  float4 w0a, w0b, h0a, h0b;                   // set 0
  float4 w1a, w1b, h1a, h1b;                   // set 1
  float4 w2a, w2b, h2a, h2b;                   // set 2
  float4 w3a, w3b, h3a, h3b;                   // set 3

  DN_PF(0, w0a, w0b, h0a, h0b);
  DN_PF(1, w1a, w1b, h1a, h1b);
  DN_PF(2, w2a, w2b, h2a, h2b);
  DN_PF(3, w3a, w3b, h3a, h3b);
  SB;
  DN_MM(w0a, w0b, h0a, h0b);  DN_PF(4, w0a, w0b, h0a, h0b);  SB;
  DN_MM(w1a, w1b, h1a, h1b);  DN_PF(5, w1a, w1b, h1a, h1b);  SB;
  DN_MM(w2a, w2b, h2a, h2b);  DN_PF(6, w2a, w2b, h2a, h2b);  SB;
  DN_MM(w3a, w3b, h3a, h3b);  DN_PF(7, w3a, w3b, h3a, h3b);  SB;
  DN_MM(w0a, w0b, h0a, h0b);  DN_PF(8, w0a, w0b, h0a, h0b);  SB;
  DN_MM(w1a, w1b, h1a, h1b);  DN_PF(9, w1a, w1b, h1a, h1b);  SB;
  DN_MM(w2a, w2b, h2a, h2b);
  if (klen > 10) { DN_PF(10, w2a, w2b, h2a, h2b); }
  SB;
  DN_MM(w3a, w3b, h3a, h3b);
  DN_MM(w0a, w0b, h0a, h0b);
  DN_MM(w1a, w1b, h1a, h1b);
  if (klen > 10) { DN_MM(w2a, w2b, h2a, h2b); }

#pragma unroll
  for (int r = 0; r < 4; ++r) red[w][r][l] = acc[r];
  __syncthreads();
  if (w == 0) {
    const float t20 = ws[T2_OFF + 2 * n], t21 = ws[T2_OFF + 2 * n + 1];
    const int m4 = (l >> 4) * 4;
#pragma unroll
    for (int r = 0; r < 4; ++r) {
      float v = red[0][r][l] + red[1][r][l] + red[2][r][l] + red[3][r][l];
      const int oo = tile * 16 + m4 + r;
      if (half == 0)
        v += 0.5f * (t20 * b2[2 * oo] + t21 * b2[2 * oo + 1]);
      atomicAdd(&out[n * DMODEL + oo], v);
    }
  }
}

// ---------------------------------------------------------------------------
extern "C" void kernel_launch(void* const* d_in, const int* in_sizes, int n_in,
                              void* d_out, int out_size, void* d_ws, size_t ws_size,
                              hipStream_t stream) {
  const float* x   = (const float*)d_in[0];
  const float* w1q = (const float*)d_in[1];
  const float* a1  = (const float*)d_in[2];
  const float* b1  = (const float*)d_in[3];
  const float* w3q = (const float*)d_in[4];
  const float* a3  = (const float*)d_in[5];
  const float* b3  = (const float*)d_in[6];
  const float* w2q = (const float*)d_in[7];
  const float* a2  = (const float*)d_in[8];
  const float* b2  = (const float*)d_in[9];
  float* out = (float*)d_out;
  float* ws  = (float*)d_ws;

  k_prep1<<<16, 256, 0, stream>>>(x, a1, a3, ws, out);
  k_gateup<<<HID / 16, 256, 0, stream>>>(w1q, w3q, b1, b3, a2, ws);
  k_down<<<2 * (DMODEL / 16), 256, 0, stream>>>(w2q, b2, ws, out);
}